// Round 8
// baseline (177.287 us; speedup 1.0000x reference)
//
#include <hip/hip_runtime.h>
#include <hip/hip_bf16.h>

// MyConv1d_ell_2_sequential: B=16384, C=128, O=128, LIN=18, out (B,128,54) fp32.
// out[b,o,t*6+l] = sum over tap instances (j, i, coef) of coef * sum_c x[b,c,i]*Fj[c,o]
// R2: LDS-transpose epilogue -> coalesced float4 stores (286 -> 188 us).
// R5: + filter pre-pack to MFMA B-frags in d_ws (188 -> 145 us).
// R6: lgkm-only epilogue barriers: NEUTRAL (drains weren't the cost).
// R7: persistent 2-tile blocks (grid 512): during tile0's store-out epilogue,
//     interleave tile1's staging reads (1 load + 2 LDS writes per chunk) so
//     HBM reads overlap the store stream. ~164 arch regs/thread => ~1 block/CU
//     resident; phases serialize at CU level, so overlap must be intra-block.
// R8: fix compile error (pragma mid-line in switch); logic identical to R7.

using short8 = short __attribute__((ext_vector_type(8)));
using f32x4  = float __attribute__((ext_vector_type(4)));

#define DEVINL __device__ __forceinline__

DEVINL unsigned short f2bf(float f) {
    unsigned int u = __float_as_uint(f);
    unsigned int r = u + 0x7FFFu + ((u >> 16) & 1u);   // RNE
    return (unsigned short)(r >> 16);
}

// lgkm-only fence + raw barrier (R6: equivalent to __syncthreads here)
DEVINL void lds_bar() {
    asm volatile("s_waitcnt lgkmcnt(0)" ::: "memory");
    __builtin_amdgcn_s_barrier();
}

// instance tables: per i (0..14), list of (acc slot, filter plane j)
__constant__ constexpr int START[16] = {0,6,12,18,23,31,37,46,54,63,69,77,82,88,94,100};
__constant__ constexpr int SLOT[100] = {
 0,1,2,3,3,4,
 1,2,3,4,4,5,
 6,7,8,9,9,10,
 7,8,9,10,10,
 0,11,12,13,2,14,14,3,
 12,1,13,14,3,4,
 15,6,16,1,17,8,9,3,4,
 16,7,17,2,9,10,4,5,
 18,11,19,7,13,2,14,9,10,
 19,12,8,14,3,10,
 20,15,12,17,8,14,3,3,
 16,13,9,4,4,
 18,16,13,9,9,4,
 19,17,14,10,10,5,
 20,19,17,14,14,10
};
__constant__ constexpr int JJ[100] = {
 0,0,2,2,2,2,
 0,0,2,2,2,2,
 0,0,2,2,2,2,
 0,0,2,2,2,
 1,0,0,2,3,2,2,3,
 0,1,0,2,3,3,
 0,1,0,1,2,3,3,3,3,
 0,1,0,1,3,3,3,3,
 0,1,0,1,3,4,3,3,3,
 0,1,1,3,4,3,
 0,1,1,3,4,3,4,4,
 1,1,4,4,4,
 1,1,4,4,4,4,
 1,1,4,4,4,4,
 1,1,4,4,4,4
};
// slot -> u (column in 0..53); remaining 33 columns are structural zeros
__constant__ constexpr int UCOL[21] = {0,1,2,3,4,5,6,7,8,9,10,12,13,14,15,18,19,20,24,25,30};

// ---- pre-kernel: pack filters into MFMA B-fragments (bf16, pre-scaled) ----
// bp layout: [wid(8)][j(5)][q(4)][lane(64)] x short8  (160 KB total)
__global__ __launch_bounds__(256)
void pack_filters(const float* __restrict__ f2, const float* __restrict__ f3,
                  unsigned short* __restrict__ bp)
{
    int p = blockIdx.x * 256 + threadIdx.x;       // 0..10239
    if (p >= 10240) return;
    int L   = p & 63;
    int t   = p >> 6;                             // wid*20 + j*4 + q
    int q   = t & 3;
    int j   = (t >> 2) % 5;
    int wid = t / 20;
    int o   = wid * 16 + (L & 15);
    int c0  = q * 32 + (L >> 4) * 8;
    float scale = (j < 2) ? 0.0625f : 0.051031036307982884f;
    unsigned short v[8];
    #pragma unroll
    for (int e = 0; e < 8; ++e) {
        int c = c0 + e;
        float f = (j < 2) ? f2[(o * 128 + c) * 2 + j]
                          : f3[(o * 128 + c) * 3 + (j - 2)];
        v[e] = f2bf(f * scale);
    }
    *reinterpret_cast<short8*>(bp + (long)p * 8) = *reinterpret_cast<const short8*>(v);
}

__global__ __launch_bounds__(512, 2)
void conv1d_ell_kernel(const float* __restrict__ x,
                       const unsigned short* __restrict__ bpack,
                       float* __restrict__ out)
{
    // xl: x tile bf16 [i(15)][b(16)][c(128)] XOR-swizzled         61440 B
    // ob: epilogue half-row float buffer [o_half(64)][u(54)]      13824 B
    __shared__ __align__(16) unsigned char smem[75264];
    unsigned short* xl = reinterpret_cast<unsigned short*>(smem);
    float*          ob = reinterpret_cast<float*>(smem + 61440);

    const int tid  = threadIdx.x;
    const int lane = tid & 63;
    const int wid  = tid >> 6;          // 0..7  -> o tile = wid*16
    const int m    = lane & 15;
    const int kblk = lane >> 4;         // 0..3
    const int g    = lane >> 4;         // D row group
    const int oc   = wid * 16 + m;

    const long b0row = (long)blockIdx.x * 32;   // tile0: rows [b0row, +16), tile1: [+16, +32)

    // ---- full stage of a 16-row tile (R5 pattern) ----
    auto stage_full = [&](long bbase) {
        #pragma unroll
        for (int q = 0; q < 4; ++q) {
            int r = tid + q * 512;
            int b = r >> 7;
            int c = r & 127;
            const float* px = x + (bbase + b) * 2304 + (long)c * 18;
            float v[16];
            #pragma unroll
            for (int t = 0; t < 8; ++t) {
                float2 w = reinterpret_cast<const float2*>(px)[t];
                v[2*t] = w.x; v[2*t+1] = w.y;
            }
            #pragma unroll
            for (int i = 0; i < 15; ++i) {
                int idx = (i * 2048 + b * 128 + c) ^ ((b & 7) << 3);
                xl[idx] = f2bf(v[i]);
            }
        }
    };

    // ---- load pre-packed filter B-fragments: 20 coalesced 16B loads ----
    short8 bfrag[5][4];
    {
        const unsigned short* bp = bpack + ((long)(wid * 20) * 64 + lane) * 8;
        #pragma unroll
        for (int j = 0; j < 5; ++j)
            #pragma unroll
            for (int q = 0; q < 4; ++q)
                bfrag[j][q] = *reinterpret_cast<const short8*>(bp + (long)(j * 4 + q) * 64 * 8);
    }

    f32x4 acc[21];
    auto acc_zero = [&]() {
        #pragma unroll
        for (int s = 0; s < 21; ++s) acc[s] = (f32x4){0.f, 0.f, 0.f, 0.f};
    };

    auto compute = [&]() {
        #pragma unroll
        for (int i = 0; i < 15; ++i) {
            short8 a[4];
            #pragma unroll
            for (int q = 0; q < 4; ++q) {
                int c0 = q * 32 + kblk * 8;
                int idx = (i * 2048 + m * 128 + c0) ^ ((m & 7) << 3);
                a[q] = *reinterpret_cast<const short8*>(&xl[idx]);
            }
            #pragma unroll
            for (int n = START[i]; n < START[i + 1]; ++n) {
                const int s = SLOT[n];
                const int j = JJ[n];
                #pragma unroll
                for (int q = 0; q < 4; ++q) {
                    acc[s] = __builtin_amdgcn_mfma_f32_16x16x32_bf16(a[q], bfrag[j][q], acc[s], 0, 0, 0);
                }
            }
        }
    };

    // scatter one (row k, o-half h) into ob; static acc lane index (rule #20)
    auto scatter = [&](int k, int h) {
        if (g == (k >> 2) && (wid >> 2) == h) {
            float* dst = ob + (oc & 63) * 54;   // word stride 54: 16 distinct banks/wave
            const int r = k & 3;
            if (r == 0) {
                #pragma unroll
                for (int s = 0; s < 21; ++s) dst[UCOL[s]] = acc[s][0];
            } else if (r == 1) {
                #pragma unroll
                for (int s = 0; s < 21; ++s) dst[UCOL[s]] = acc[s][1];
            } else if (r == 2) {
                #pragma unroll
                for (int s = 0; s < 21; ++s) dst[UCOL[s]] = acc[s][2];
            } else {
                #pragma unroll
                for (int s = 0; s < 21; ++s) dst[UCOL[s]] = acc[s][3];
            }
        }
    };

    // ========================= tile 0 =========================
    stage_full(b0row);
    // zero-fill ob once (864 float4); structural zeros persist across all chunks
    {
        float4 z = make_float4(0.f, 0.f, 0.f, 0.f);
        *reinterpret_cast<float4*>(ob + 4 * tid) = z;
        if (tid < 352) *reinterpret_cast<float4*>(ob + 4 * (tid + 512)) = z;
    }
    acc_zero();
    __syncthreads();
    compute();

    // ---- epilogue t0, interleaving tile1 staging (1/32 per chunk) ----
    #pragma unroll 1
    for (int cc = 0; cc < 32; ++cc) {
        const int k = cc >> 1, h = cc & 1;
        scatter(k, h);
        lds_bar();
        {   // copy half-row (3456 floats) out, fully coalesced
            float* dstg = out + (b0row + k) * 6912 + h * 3456;
            float4 w0 = *reinterpret_cast<const float4*>(ob + 4 * tid);
            *reinterpret_cast<float4*>(dstg + 4 * tid) = w0;
            if (tid < 352) {
                float4 w1 = *reinterpret_cast<const float4*>(ob + 4 * (tid + 512));
                *reinterpret_cast<float4*>(dstg + 4 * (tid + 512)) = w1;
            }
        }
        {   // tile1 staging step cc: 1 float2 load + <=2 LDS writes
            const int q = cc >> 3, f = cc & 7;
            const int r2 = tid + q * 512;
            const int b = r2 >> 7, c = r2 & 127;
            float2 w = *reinterpret_cast<const float2*>(
                x + (b0row + 16 + b) * 2304 + (long)c * 18 + 2 * f);
            const int i0 = 2 * f;
            xl[(i0 * 2048 + b * 128 + c) ^ ((b & 7) << 3)] = f2bf(w.x);
            if (f < 7)
                xl[((i0 + 1) * 2048 + b * 128 + c) ^ ((b & 7) << 3)] = f2bf(w.y);
        }
        lds_bar();
    }

    // ========================= tile 1 =========================
    acc_zero();
    compute();

    #pragma unroll 1
    for (int cc = 0; cc < 32; ++cc) {
        const int k = cc >> 1, h = cc & 1;
        scatter(k, h);
        lds_bar();
        {
            float* dstg = out + (b0row + 16 + k) * 6912 + h * 3456;
            float4 w0 = *reinterpret_cast<const float4*>(ob + 4 * tid);
            *reinterpret_cast<float4*>(dstg + 4 * tid) = w0;
            if (tid < 352) {
                float4 w1 = *reinterpret_cast<const float4*>(ob + 4 * (tid + 512));
                *reinterpret_cast<float4*>(dstg + 4 * (tid + 512)) = w1;
            }
        }
        lds_bar();
    }
}

extern "C" void kernel_launch(void* const* d_in, const int* in_sizes, int n_in,
                              void* d_out, int out_size, void* d_ws, size_t ws_size,
                              hipStream_t stream) {
    const float* x   = (const float*)d_in[0];
    const float* sos = (const float*)d_in[1];
    const float* f2  = (const float*)d_in[2];
    const float* f3  = (const float*)d_in[3];
    float* out = (float*)d_out;
    unsigned short* bp = (unsigned short*)d_ws;    // 160 KB of fragments

    pack_filters<<<dim3(40), dim3(256), 0, stream>>>(f2, f3, bp);
    conv1d_ell_kernel<<<dim3(512), dim3(512), 0, stream>>>(x, bp, out);

    // output 1: pass-through copy of sum_of_squares (16384 floats)
    (void)hipMemcpyAsync(out + 113246208LL, sos, 16384 * sizeof(float),
                         hipMemcpyDeviceToDevice, stream);
}

// Round 10
// 141.805 us; speedup vs baseline: 1.2502x; 1.2502x over previous
//
#include <hip/hip_runtime.h>
#include <hip/hip_bf16.h>

// MyConv1d_ell_2_sequential: B=16384, C=128, O=128, LIN=18, out (B,128,54) fp32.
// out[b,o,t*6+l] = sum over tap instances (j, i, coef) of coef * sum_c x[b,c,i]*Fj[c,o]
// R2: LDS-transpose epilogue -> coalesced float4 stores (286 -> 188 us).
// R5: + filter pre-pack to MFMA B-frags in d_ws (188 -> 145 us).
// R6: lgkm-only epilogue barriers: NEUTRAL. R8: fine-grained interleave: WORSE (177).
// R9: zero-barrier PER-WAVE epilogue. Wave w's output for row k, o in [16w,16w+16)
//     is a contiguous 3456-B region -> scatter+transpose+store in a private
//     3456-B LDS buffer, DS-in-order within the wave, NO s_barrier. Exactly one
//     __syncthreads in the kernel (after staging). ~210 regs/wave => 1 block/CU;
//     wave-independent epilogue lets stores flow and blocks hand off early.
// R10: resubmit of R9 (container died before benching).

using short8 = short __attribute__((ext_vector_type(8)));
using f32x4  = float __attribute__((ext_vector_type(4)));

#define DEVINL __device__ __forceinline__

DEVINL unsigned short f2bf(float f) {
    unsigned int u = __float_as_uint(f);
    unsigned int r = u + 0x7FFFu + ((u >> 16) & 1u);   // RNE
    return (unsigned short)(r >> 16);
}

// instance tables: per i (0..14), list of (acc slot, filter plane j)
__constant__ constexpr int START[16] = {0,6,12,18,23,31,37,46,54,63,69,77,82,88,94,100};
__constant__ constexpr int SLOT[100] = {
 0,1,2,3,3,4,
 1,2,3,4,4,5,
 6,7,8,9,9,10,
 7,8,9,10,10,
 0,11,12,13,2,14,14,3,
 12,1,13,14,3,4,
 15,6,16,1,17,8,9,3,4,
 16,7,17,2,9,10,4,5,
 18,11,19,7,13,2,14,9,10,
 19,12,8,14,3,10,
 20,15,12,17,8,14,3,3,
 16,13,9,4,4,
 18,16,13,9,9,4,
 19,17,14,10,10,5,
 20,19,17,14,14,10
};
__constant__ constexpr int JJ[100] = {
 0,0,2,2,2,2,
 0,0,2,2,2,2,
 0,0,2,2,2,2,
 0,0,2,2,2,
 1,0,0,2,3,2,2,3,
 0,1,0,2,3,3,
 0,1,0,1,2,3,3,3,3,
 0,1,0,1,3,3,3,3,
 0,1,0,1,3,4,3,3,3,
 0,1,1,3,4,3,
 0,1,1,3,4,3,4,4,
 1,1,4,4,4,
 1,1,4,4,4,4,
 1,1,4,4,4,4,
 1,1,4,4,4,4
};
// slot -> u (column in 0..53); remaining 33 columns are structural zeros
__constant__ constexpr int UCOL[21] = {0,1,2,3,4,5,6,7,8,9,10,12,13,14,15,18,19,20,24,25,30};

// ---- pre-kernel: pack filters into MFMA B-fragments (bf16, pre-scaled) ----
// bp layout: [wid(8)][j(5)][q(4)][lane(64)] x short8  (160 KB total)
__global__ __launch_bounds__(256)
void pack_filters(const float* __restrict__ f2, const float* __restrict__ f3,
                  unsigned short* __restrict__ bp)
{
    int p = blockIdx.x * 256 + threadIdx.x;       // 0..10239
    if (p >= 10240) return;
    int L   = p & 63;
    int t   = p >> 6;                             // wid*20 + j*4 + q
    int q   = t & 3;
    int j   = (t >> 2) % 5;
    int wid = t / 20;
    int o   = wid * 16 + (L & 15);
    int c0  = q * 32 + (L >> 4) * 8;
    float scale = (j < 2) ? 0.0625f : 0.051031036307982884f;
    unsigned short v[8];
    #pragma unroll
    for (int e = 0; e < 8; ++e) {
        int c = c0 + e;
        float f = (j < 2) ? f2[(o * 128 + c) * 2 + j]
                          : f3[(o * 128 + c) * 3 + (j - 2)];
        v[e] = f2bf(f * scale);
    }
    *reinterpret_cast<short8*>(bp + (long)p * 8) = *reinterpret_cast<const short8*>(v);
}

__global__ __launch_bounds__(512, 2)
void conv1d_ell_kernel(const float* __restrict__ x,
                       const unsigned short* __restrict__ bpack,
                       float* __restrict__ out)
{
    // xl: x tile bf16 [i(15)][b(16)][c(128)] XOR-swizzled          61440 B
    // ob: 8 per-wave float buffers [m(16)][u(54)] = 8 x 3456 B     27648 B
    __shared__ __align__(16) unsigned char smem[89088];
    unsigned short* xl = reinterpret_cast<unsigned short*>(smem);
    float*          ob = reinterpret_cast<float*>(smem + 61440);

    const int tid  = threadIdx.x;
    const int lane = tid & 63;
    const int wid  = tid >> 6;          // 0..7  -> o tile = wid*16
    const int m    = lane & 15;
    const int kblk = lane >> 4;         // 0..3
    const int g    = lane >> 4;         // D row group

    const long b_base = (long)blockIdx.x * 16;

    // ---- stage x -> LDS (fp32 -> bf16, transpose (b,c,i)->(i,b,c)) ----
    #pragma unroll
    for (int q = 0; q < 4; ++q) {
        int r = tid + q * 512;          // 0..2047
        int b = r >> 7;
        int c = r & 127;
        const float* px = x + (b_base + b) * 2304 + (long)c * 18;
        float v[16];
        #pragma unroll
        for (int t = 0; t < 8; ++t) {
            float2 w = reinterpret_cast<const float2*>(px)[t];
            v[2*t] = w.x; v[2*t+1] = w.y;
        }
        #pragma unroll
        for (int i = 0; i < 15; ++i) {
            int idx = (i * 2048 + b * 128 + c) ^ ((b & 7) << 3);
            xl[idx] = f2bf(v[i]);
        }
    }

    // ---- load pre-packed filter B-fragments: 20 coalesced 16B loads ----
    short8 bfrag[5][4];
    {
        const unsigned short* bp = bpack + ((long)(wid * 20) * 64 + lane) * 8;
        #pragma unroll
        for (int j = 0; j < 5; ++j)
            #pragma unroll
            for (int q = 0; q < 4; ++q)
                bfrag[j][q] = *reinterpret_cast<const short8*>(bp + (long)(j * 4 + q) * 64 * 8);
    }

    f32x4 acc[21];
    #pragma unroll
    for (int s = 0; s < 21; ++s) acc[s] = (f32x4){0.f, 0.f, 0.f, 0.f};

    __syncthreads();                    // the ONLY barrier in the kernel

    // ---- main loop ----
    #pragma unroll
    for (int i = 0; i < 15; ++i) {
        short8 a[4];
        #pragma unroll
        for (int q = 0; q < 4; ++q) {
            int c0 = q * 32 + kblk * 8;
            int idx = (i * 2048 + m * 128 + c0) ^ ((m & 7) << 3);
            a[q] = *reinterpret_cast<const short8*>(&xl[idx]);
        }
        #pragma unroll
        for (int n = START[i]; n < START[i + 1]; ++n) {
            const int s = SLOT[n];
            const int j = JJ[n];
            #pragma unroll
            for (int q = 0; q < 4; ++q) {
                acc[s] = __builtin_amdgcn_mfma_f32_16x16x32_bf16(a[q], bfrag[j][q], acc[s], 0, 0, 0);
            }
        }
    }

    // ---- per-wave epilogue: zero barriers ----
    // Wave w's data for row k: lanes with g==k>>2 hold acc[.][k&3] at o=16w+m.
    // Output region (row b_base+k, o in [16w,16w+16)) = contiguous 3456 B.
    // DS ops execute in order within a wave -> write/read hazards are safe.
    float* wbuf = ob + wid * 864;       // [m(16)][u(54)] private to this wave

    {   // zero-fill once; scatter rewrites the same 21 cols every row
        float4 z = make_float4(0.f, 0.f, 0.f, 0.f);
        #pragma unroll
        for (int t = 0; t < 3; ++t)
            *reinterpret_cast<float4*>(wbuf + 4 * (lane + 64 * t)) = z;
        if (lane < 24)
            *reinterpret_cast<float4*>(wbuf + 4 * (lane + 192)) = z;
    }

    #pragma unroll
    for (int k = 0; k < 16; ++k) {
        if (g == (k >> 2)) {            // 16 lanes scatter row k (static reg idx)
            float* dst = wbuf + m * 54; // word stride 54 -> 16 distinct banks
            #pragma unroll
            for (int s = 0; s < 21; ++s) dst[UCOL[s]] = acc[s][k & 3];
        }
        // compiler fence: keep copy reads after scatter writes (HW is in-order)
        asm volatile("s_waitcnt lgkmcnt(0)" ::: "memory");
        float* dstg = out + ((b_base + k) * 128 + wid * 16) * 54;
        #pragma unroll
        for (int t = 0; t < 3; ++t) {
            float4 w = *reinterpret_cast<const float4*>(wbuf + 4 * (lane + 64 * t));
            *reinterpret_cast<float4*>(dstg + 4 * (lane + 64 * t)) = w;
        }
        if (lane < 24) {
            float4 w = *reinterpret_cast<const float4*>(wbuf + 4 * (lane + 192));
            *reinterpret_cast<float4*>(dstg + 4 * (lane + 192)) = w;
        }
    }
}

extern "C" void kernel_launch(void* const* d_in, const int* in_sizes, int n_in,
                              void* d_out, int out_size, void* d_ws, size_t ws_size,
                              hipStream_t stream) {
    const float* x   = (const float*)d_in[0];
    const float* sos = (const float*)d_in[1];
    const float* f2  = (const float*)d_in[2];
    const float* f3  = (const float*)d_in[3];
    float* out = (float*)d_out;
    unsigned short* bp = (unsigned short*)d_ws;    // 160 KB of fragments

    pack_filters<<<dim3(40), dim3(256), 0, stream>>>(f2, f3, bp);
    conv1d_ell_kernel<<<dim3(1024), dim3(512), 0, stream>>>(x, bp, out);

    // output 1: pass-through copy of sum_of_squares (16384 floats)
    (void)hipMemcpyAsync(out + 113246208LL, sos, 16384 * sizeof(float),
                         hipMemcpyDeviceToDevice, stream);
}